// Round 8
// baseline (8868.633 us; speedup 1.0000x reference)
//
#include <hip/hip_runtime.h>

// GRU layer, B=64 T=512 D=512 H=1024, TF GRUCell semantics.
// v8: self-validating exchange words -- every published h / r*h element is
// u32 = (bf16<<16)|epoch. Consumers poll the payload itself (re-issuing stale
// words); no flags, no producer drains, 1 fabric RTT per handoff instead of 3.

#define NTHR 256
#define RPI  16               // rows per island (4 islands)
#define TT   512
#define DD   512
#define HH   1024
#define AP   520              // staged-A half-K row stride (elems); 260w = 4 mod 32
#define WPG  1544             // gate weight stride; 772w = 4 mod 32 (16B aligned)
#define WPC  1028             // cand/u weight stride; 514w = 2 mod 32

// LDS elem offsets
#define R_XS   49408          // R: Wg[32][1544] @0, Xs[16][520], Ash[16][520]
#define R_ASH  57728
#define C_WC   32896          // C: Wu[32][1028] @0, Wc[32][1028], Ash[16][520]
#define C_ASH  65792
#define LDS_BYTES 148224
#define XP_LDSB   149760      // xproj: Bc[64][520], Bu[64][520], Axs[16][520]

// ws layout (bytes): u32 words (bf16<<16 | epoch)
#define WS_HB    4096         // hb [64][1024] u32 (262144 B)
#define WS_RHB   266240       // rhb[64][1024] u32 (262144 B)
#define WS_NEED  528384       // proven available in r2

#define POLL_CAP (1 << 12)

typedef __attribute__((ext_vector_type(8))) short          s16x8;
typedef __attribute__((ext_vector_type(4))) float          f32x4;
typedef __attribute__((ext_vector_type(4))) unsigned short us4;
typedef unsigned long long ull;
typedef unsigned short us;

__device__ __forceinline__ us f2b(float f) {               // f32 -> bf16 RNE
  unsigned u = __float_as_uint(f);
  u += 0x7FFFu + ((u >> 16) & 1u);
  return (us)(u >> 16);
}
__device__ __forceinline__ float b2f(us b) { return __uint_as_float(((unsigned)b) << 16); }

// ---- device-coherent (sc1) primitives -------------------------------------
__device__ __forceinline__ ull cload8(const unsigned* p) {
  return __hip_atomic_load((const ull*)p, __ATOMIC_RELAXED, __HIP_MEMORY_SCOPE_AGENT);
}
__device__ __forceinline__ void cstore4(unsigned* p, unsigned v) {
  __hip_atomic_store(p, v, __ATOMIC_RELAXED, __HIP_MEMORY_SCOPE_AGENT);
}

// ---- self-validating half-K staging ---------------------------------------
// thread (row=tid>>4, lp=tid&15) covers cols lp*4 + j*64 (j<8) of a 512 half;
// each col is one u32 (val<<16|ep); 16x 8B loads per half.
struct HB16 { ull w[16]; };

__device__ __forceinline__ void issue_half(HB16& h, const unsigned* base) {
  #pragma unroll
  for (int j = 0; j < 8; ++j) {
    h.w[2*j]   = cload8(base + j * 64);
    h.w[2*j+1] = cload8(base + j * 64 + 2);
  }
}
// dead: skip polling entirely (fast path after a failure). Returns ok.
__device__ __forceinline__ bool poll_half(HB16& h, const unsigned* base, unsigned ep,
                                          bool dead) {
  if (dead) return false;
  unsigned pend = 0xFFFFu;
  for (int polls = 0; ; ) {
    unsigned np = 0;
    #pragma unroll
    for (int i = 0; i < 16; ++i) if (pend & (1u << i)) {
      ull w = h.w[i];
      if (((unsigned)w & 0xFFFFu) != ep || ((unsigned)(w >> 32) & 0xFFFFu) != ep)
        np |= 1u << i;
    }
    if (!np) return true;
    if (++polls > POLL_CAP) return false;
    __builtin_amdgcn_s_sleep(1);
    #pragma unroll
    for (int i = 0; i < 16; ++i) if (np & (1u << i))
      h.w[i] = cload8(base + (i >> 1) * 64 + (i & 1) * 2);
    pend = np;
  }
}
__device__ __forceinline__ void write_half(const HB16& h, us* Ash, int row, int lp) {
  us* d = Ash + row * AP + lp * 4;
  #pragma unroll
  for (int j = 0; j < 8; ++j) {
    ull w0 = h.w[2*j], w1 = h.w[2*j+1];
    unsigned lo = ((unsigned)(w0 >> 16) & 0xFFFFu) | ((unsigned)(w0 >> 48) << 16);
    unsigned hi = ((unsigned)(w1 >> 16) & 0xFFFFu) | ((unsigned)(w1 >> 48) << 16);
    *(ull*)(d + j * 64) = (ull)lo | ((ull)hi << 32);
  }
}

// stage x(t) [16 rows x 512] f32->bf16 into Xs (plain loads; X is read-only)
__device__ __forceinline__ void stage_xs(us* Xs, const float* X, int islbase, int t,
                                         int row, int lp) {
  const float* src = X + ((size_t)(islbase + row) * TT + t) * DD + lp * 4;
  us* d = Xs + row * AP + lp * 4;
  #pragma unroll
  for (int j = 0; j < 8; ++j) {
    float4 v = *(const float4*)(src + j * 64);
    us4 p = { f2b(v.x), f2b(v.y), f2b(v.z), f2b(v.w) };
    *(us4*)(d + j * 64) = p;
  }
}

// one 16x16 tile, K=512 half: 16 MFMA, 2 accumulators
__device__ __forceinline__ void mm_half(const us* A, const us* W, int wst, int kbase,
                                        int cc, int r16, int g4, f32x4& a0, f32x4& a1) {
  const us* ar = A + r16 * AP + g4 * 8;
  const us* br = W + cc * wst + kbase + g4 * 8;
  #pragma unroll
  for (int f = 0; f < 16; f += 2) {
    s16x8 av0 = *(const s16x8*)(ar + f * 32);
    s16x8 bv0 = *(const s16x8*)(br + f * 32);
    s16x8 av1 = *(const s16x8*)(ar + f * 32 + 32);
    s16x8 bv1 = *(const s16x8*)(br + f * 32 + 32);
    a0 = __builtin_amdgcn_mfma_f32_16x16x32_bf16(av0, bv0, a0, 0, 0, 0);
    a1 = __builtin_amdgcn_mfma_f32_16x16x32_bf16(av1, bv1, a1, 0, 0, 0);
  }
}

extern "C" __global__ void __launch_bounds__(NTHR, 1)
gru_persistent(const float* __restrict__ X, const float* __restrict__ GK,
               const float* __restrict__ GB, const float* __restrict__ CK,
               const float* __restrict__ CB, float* __restrict__ Y,
               unsigned char* __restrict__ ws) {
  extern __shared__ us lds[];
  const int tid = threadIdx.x, bid = blockIdx.x;
  const int isl = (bid & 7) >> 1;                  // XCD pair {2i,2i+1}
  const int iw  = ((bid >> 3) << 1) | (bid & 1);   // 0..63 within island
  const int islbase = isl * RPI;
  const int lane = tid & 63, w = tid >> 6;
  const int r16 = lane & 15, g4 = lane >> 4;
  const int ct = w & 1;                            // col-tile (waves 2,3 duplicate)
  const int srow = tid >> 4, slp = tid & 15;       // staging map

  unsigned* hbw = (unsigned*)(ws + WS_HB);         // h  words (val<<16|ep)
  unsigned* rhw = (unsigned*)(ws + WS_RHB);        // rh words

  bool bad = false;

  if (iw < 32) {
    // ================= R-WG: 32 reset-gate cols, publish r*h =================
    us* Wg  = lds;                                 // [32][WPG]
    us* Xs  = lds + R_XS;                          // [16][AP]
    us* Ash = lds + R_ASH;                         // [16][AP]
    const int cbase = iw * 32;
    {
      const int c = tid & 31;
      for (int k = tid >> 5; k < 1536; k += 8)
        Wg[c * WPG + k] = f2b(GK[(size_t)k * 2048 + cbase + c]);
    }
    const int   cc   = ct * 16 + r16;
    const int   col  = cbase + cc;
    const float bias = GB[col];
    const int   H    = (cbase >= 512);             // which half holds own cols
    const unsigned* hrow = hbw + (size_t)(islbase + srow) * HH + slp * 4;
    stage_xs(Xs, X, islbase, 0, srow, slp);
    __syncthreads();

    for (int t = 0; t < TT; ++t) {
      const unsigned epH = (unsigned)t & 0xFFFFu;        // h(t-1) epoch
      HB16 h0, h1;
      issue_half(h0, hrow);                              // 32 loads in flight
      issue_half(h1, hrow + 512);
      f32x4 a0 = {0.f,0.f,0.f,0.f}, a1 = {0.f,0.f,0.f,0.f};
      mm_half(Xs, Wg, WPG, 0, cc, r16, g4, a0, a1);      // x-part under RTT
      bad |= !poll_half(h0, hrow, epH, bad);
      write_half(h0, Ash, srow, slp);
      __syncthreads();
      float hv[4];
      if (!H) {
        #pragma unroll
        for (int i = 0; i < 4; ++i) hv[i] = b2f(Ash[(g4 * 4 + i) * AP + col]);
      }
      mm_half(Ash, Wg, WPG, 512, cc, r16, g4, a0, a1);
      bad |= !poll_half(h1, hrow + 512, epH, bad);
      __syncthreads();
      write_half(h1, Ash, srow, slp);
      __syncthreads();
      mm_half(Ash, Wg, WPG, 1024, cc, r16, g4, a0, a1);
      if (H) {
        #pragma unroll
        for (int i = 0; i < 4; ++i) hv[i] = b2f(Ash[(g4 * 4 + i) * AP + (col - 512)]);
      }
      const unsigned ep1 = (unsigned)(t + 1) & 0xFFFFu;
      #pragma unroll
      for (int i = 0; i < 4; ++i) {                      // C/D: row=g4*4+i, col=r16
        float rv = 1.f / (1.f + __expf(-(a0[i] + a1[i] + bias)));
        if (w < 2)
          cstore4(rhw + (size_t)(islbase + g4 * 4 + i) * HH + col,
                  ((unsigned)f2b(rv * hv[i]) << 16) | ep1);   // fire-and-forget
      }
      if (t + 1 < TT) stage_xs(Xs, X, islbase, t + 1, srow, slp);
      __syncthreads();                                   // Xs(t+1) + Ash free
    }
  } else {
    // ====== C-WG: 32 cols; local u-gate (off exchange) + cand + h update ======
    us* Wu  = lds;                                 // [32][WPC]
    us* Wc  = lds + C_WC;                          // [32][WPC]
    us* Ash = lds + C_ASH;                         // [16][AP]
    const int ic = iw - 32, cbase = ic * 32;
    {
      const int c = tid & 31;
      for (int k = tid >> 5; k < 1024; k += 8) {
        Wu[c * WPC + k] = f2b(GK[(size_t)(512 + k) * 2048 + 1024 + cbase + c]);
        Wc[c * WPC + k] = f2b(CK[(size_t)(512 + k) * 1024 + cbase + c]);
      }
    }
    const int   cc    = ct * 16 + r16;
    const int   col   = cbase + cc;
    const float ubias = GB[1024 + col];
    const float cbias = CB[col];
    float hreg[4] = {0.f, 0.f, 0.f, 0.f};
    const unsigned* Yw = (const unsigned*)Y;
    const unsigned* hrow = hbw + (size_t)(islbase + srow) * HH + slp * 4;
    const unsigned* rrow = rhw + (size_t)(islbase + srow) * HH + slp * 4;
    __syncthreads();

    for (int t = 0; t < TT; ++t) {
      const unsigned epH = (unsigned)t & 0xFFFFu;
      const unsigned ep1 = (unsigned)(t + 1) & 0xFFFFu;
      unsigned xw[4];                              // packed (xp_u<<16 | xp_c)
      #pragma unroll
      for (int i = 0; i < 4; ++i)
        xw[i] = Yw[((size_t)(islbase + g4 * 4 + i) * TT + t) * HH + col];
      HB16 b0, b1;
      issue_half(b0, hrow);
      issue_half(b1, hrow + 512);
      // ---- u-GEMM over h(t-1): overlaps R phase ----
      f32x4 u0 = {0.f,0.f,0.f,0.f}, u1 = {0.f,0.f,0.f,0.f};
      bad |= !poll_half(b0, hrow, epH, bad);
      write_half(b0, Ash, srow, slp);
      __syncthreads();
      mm_half(Ash, Wu, WPC, 0, cc, r16, g4, u0, u1);
      bad |= !poll_half(b1, hrow + 512, epH, bad);
      __syncthreads();
      write_half(b1, Ash, srow, slp);
      __syncthreads();
      mm_half(Ash, Wu, WPC, 512, cc, r16, g4, u0, u1);
      float uv[4];
      #pragma unroll
      for (int i = 0; i < 4; ++i)
        uv[i] = 1.f / (1.f + __expf(-(u0[i] + u1[i] +
                    b2f((us)(xw[i] >> 16)) + ubias)));
      // ---- cand GEMM over r*h(t) ----
      issue_half(b0, rrow);
      issue_half(b1, rrow + 512);
      f32x4 c0 = {0.f,0.f,0.f,0.f}, c1 = {0.f,0.f,0.f,0.f};
      bad |= !poll_half(b0, rrow, ep1, bad);
      __syncthreads();                             // all waves done u reads of Ash
      write_half(b0, Ash, srow, slp);
      __syncthreads();
      mm_half(Ash, Wc, WPC, 0, cc, r16, g4, c0, c1);
      bad |= !poll_half(b1, rrow + 512, ep1, bad);
      __syncthreads();
      write_half(b1, Ash, srow, slp);
      __syncthreads();
      mm_half(Ash, Wc, WPC, 512, cc, r16, g4, c0, c1);
      #pragma unroll
      for (int i = 0; i < 4; ++i) {
        float cv = tanhf(c0[i] + c1[i] + b2f((us)(xw[i] & 0xFFFF)) + cbias);
        float hn = uv[i] * hreg[i] + (1.f - uv[i]) * cv;
        hreg[i] = hn;
        if (w < 2) {
          Y[((size_t)(islbase + g4 * 4 + i) * TT + t) * HH + col] = hn;
          cstore4(hbw + (size_t)(islbase + g4 * 4 + i) * HH + col,
                  ((unsigned)f2b(hn) << 16) | ep1);        // fire-and-forget
        }
      }
      __syncthreads();                             // Ash free for next iter
    }
  }
  if (bad) Y[1] = 31337.f;                         // visible failure sentinel
}

// ---- one-time dual x-projection: Yw <- pack(bf16(X@GKu), bf16(X@CKc)) ------
// grid: 16 col-panels x 64 row-blocks; B panels LDS-resident per block.
extern "C" __global__ void __launch_bounds__(NTHR, 1)
xproj_dual(const float* __restrict__ X, const float* __restrict__ CK,
           const float* __restrict__ GK, unsigned* __restrict__ Yw) {
  extern __shared__ us lds[];
  us* Bc  = lds;                 // [64][520]
  us* Bu  = lds + 64 * 520;      // [64][520]
  us* Axs = lds + 128 * 520;     // [16][520]
  const int tid = threadIdx.x, lane = tid & 63, w = tid >> 6;
  const int r16 = lane & 15, g4 = lane >> 4;
  const int nt = blockIdx.x & 15, mb = blockIdx.x >> 4;
  const int n0 = nt * 64;
  const int srow = tid >> 4, slp = tid & 15;

  {
    const int c4 = (tid & 15) * 4;
    for (int k = tid >> 4; k < 512; k += 16) {
      float4 v  = *(const float4*)(CK + (size_t)k * HH + n0 + c4);
      float4 vu = *(const float4*)(GK + (size_t)k * 2048 + 1024 + n0 + c4);
      Bc[(c4 + 0) * 520 + k] = f2b(v.x);  Bc[(c4 + 1) * 520 + k] = f2b(v.y);
      Bc[(c4 + 2) * 520 + k] = f2b(v.z);  Bc[(c4 + 3) * 520 + k] = f2b(v.w);
      Bu[(c4 + 0) * 520 + k] = f2b(vu.x); Bu[(c4 + 1) * 520 + k] = f2b(vu.y);
      Bu[(c4 + 2) * 520 + k] = f2b(vu.z); Bu[(c4 + 3) * 520 + k] = f2b(vu.w);
    }
  }
  __syncthreads();

  for (int mt = 0; mt < 32; ++mt) {
    const size_t m0 = (size_t)mb * 512 + mt * 16;
    {                                              // stage A [16][512] f32->bf16
      const float* src = X + (m0 + srow) * 512 + slp * 4;
      us* d = Axs + srow * AP + slp * 4;
      #pragma unroll
      for (int j = 0; j < 8; ++j) {
        float4 v = *(const float4*)(src + j * 64);
        us4 p = { f2b(v.x), f2b(v.y), f2b(v.z), f2b(v.w) };
        *(us4*)(d + j * 64) = p;
      }
    }
    __syncthreads();
    const int ci = w;                              // wave -> col-tile 0..3
    f32x4 ac0 = {0.f,0.f,0.f,0.f}, ac1 = {0.f,0.f,0.f,0.f};
    f32x4 au0 = {0.f,0.f,0.f,0.f}, au1 = {0.f,0.f,0.f,0.f};
    const us* ar = Axs + r16 * AP + g4 * 8;
    const us* bc = Bc + (ci * 16 + r16) * 520 + g4 * 8;
    const us* bu = Bu + (ci * 16 + r16) * 520 + g4 * 8;
    #pragma unroll
    for (int f = 0; f < 16; f += 2) {
      s16x8 a0v = *(const s16x8*)(ar + f * 32);
      s16x8 a1v = *(const s16x8*)(ar + f * 32 + 32);
      ac0 = __builtin_amdgcn_mfma_f32_16x16x32_bf16(a0v, *(const s16x8*)(bc + f * 32), ac0, 0,0,0);
      ac1 = __builtin_amdgcn_mfma_f32_16x16x32_bf16(a1v, *(const s16x8*)(bc + f * 32 + 32), ac1, 0,0,0);
      au0 = __builtin_amdgcn_mfma_f32_16x16x32_bf16(a0v, *(const s16x8*)(bu + f * 32), au0, 0,0,0);
      au1 = __builtin_amdgcn_mfma_f32_16x16x32_bf16(a1v, *(const s16x8*)(bu + f * 32 + 32), au1, 0,0,0);
    }
    #pragma unroll
    for (int i = 0; i < 4; ++i) {
      float xc = ac0[i] + ac1[i], xu = au0[i] + au1[i];
      Yw[(m0 + g4 * 4 + i) * HH + n0 + ci * 16 + r16] =
          ((unsigned)f2b(xu) << 16) | (unsigned)f2b(xc);
    }
    __syncthreads();
  }
}

extern "C" __global__ void gru_sentinel(float* out, float v) {
  if (blockIdx.x == 0 && threadIdx.x == 0) out[0] = v;
}

extern "C" void kernel_launch(void* const* d_in, const int* in_sizes, int n_in,
                              void* d_out, int out_size, void* d_ws, size_t ws_size,
                              hipStream_t stream) {
  const float* X  = (const float*)d_in[0];
  const float* GK = (const float*)d_in[1];
  const float* GB = (const float*)d_in[2];
  const float* CK = (const float*)d_in[3];
  const float* CB = (const float*)d_in[4];
  float* Y = (float*)d_out;
  unsigned char* wsb = (unsigned char*)d_ws;

  if (ws_size < (size_t)WS_NEED) {
    gru_sentinel<<<1, 64, 0, stream>>>(Y, 1000.f + (float)(ws_size >> 20));
    return;
  }

  // zero hb (h0=0, epoch 0) + rhb (stale epochs cleared) each call
  hipMemsetAsync(d_ws, 0, WS_NEED, stream);

  (void)hipFuncSetAttribute((const void*)xproj_dual,
                            hipFuncAttributeMaxDynamicSharedMemorySize, XP_LDSB);
  xproj_dual<<<dim3(16 * 64), dim3(NTHR), XP_LDSB, stream>>>(X, CK, GK, (unsigned*)Y);

  (void)hipFuncSetAttribute((const void*)gru_persistent,
                            hipFuncAttributeMaxDynamicSharedMemorySize, LDS_BYTES);
  gru_persistent<<<dim3(256), dim3(NTHR), LDS_BYTES, stream>>>(X, GK, GB, CK, CB, Y, wsb);
}

// Round 10
// 2946.005 us; speedup vs baseline: 3.0104x; 3.0104x over previous
//
#include <hip/hip_runtime.h>

// GRU layer, B=64 T=512 D=512 H=1024, TF GRUCell semantics.
// v10: merged-WG structure (every WG: gates r+u then cand for its 32 cols),
// 8 islands x 8 batch rows x 32 WGs. All cross-WG exchange via relaxed
// agent-scope __hip_atomic ops (compiler-managed waitcnt -- the r5/r7-proven
// path; no inline asm, no XCD-local gamble). r/u x-parts computed live from
// VGPR weights; Y pre-filled with f32 xp_c = X @ CKc by xproj_c.

typedef __attribute__((ext_vector_type(8))) short          s16x8;
typedef __attribute__((ext_vector_type(4))) float          f32x4;
typedef __attribute__((ext_vector_type(4))) unsigned short us4;
typedef __attribute__((ext_vector_type(8))) unsigned short us8;
typedef unsigned long long ull;
typedef unsigned short us;

#define TT 512
#define DD 512
#define HH 1024
#define WPGE 1032            // Wg stride: 516w, %32=4 -> B rows 2-way max (free)
#define ASTR 1032            // Ash stride: rows 0..7 -> bank offs {0,4,..,28} distinct
#define XSTR 520
#define O_ASH (64 * WPGE)                 // 66048
#define O_XS  (O_ASH + 8 * ASTR)          // 74304
#define O_USH (O_XS + 8 * XSTR)           // 78464 (float[8][36] = 576 us)
#define O_PS  (O_USH + 576)               // 79040 (float[2][8][20] = 640 us)
#define LDS_BYTES ((O_PS + 640) * 2)      // 159360 <= 160 KiB
#define XP_LDSB (64 * 520 * 2 + 16 * 520 * 2)   // 83200

// ws layout (bytes)
#define W_FL   0             // island isl @ isl*4096: hfl 32x64B, rfl @+2048
#define W_HB   32768         // h  bf16 [64][1024] (131072 B) -- memset 0 = h0
#define W_RHB  163840        // rh bf16 [64][1024]
#define W_END  294912
#define POLLCAP (1 << 17)

__device__ __forceinline__ us f2b(float f) {               // f32 -> bf16 RNE
  unsigned u = __float_as_uint(f);
  u += 0x7FFFu + ((u >> 16) & 1u);
  return (us)(u >> 16);
}
__device__ __forceinline__ float b2f(us b) { return __uint_as_float(((unsigned)b) << 16); }

// wait all 32 island flags >= e (uniform per wave; sticky-bad, no hang)
__device__ __forceinline__ void waitf(const unsigned* f, unsigned e, int lane, bool& bad) {
  if (bad) return;
  const unsigned* p = f + (lane & 31) * 16;                // 64B-spaced slots
  int n = 0;
  for (;;) {
    unsigned v = (lane < 32)
        ? __hip_atomic_load(p, __ATOMIC_RELAXED, __HIP_MEMORY_SCOPE_AGENT) : e;
    if (__all((int)(v >= e))) return;
    if (++n > POLLCAP) { bad = true; return; }
    __builtin_amdgcn_s_sleep(1);
  }
}

// stage 8 rows x 1024 bf16 island buffer -> Ash (thread: row8=tid>>5, lp=tid&31)
__device__ __forceinline__ void stage(const us* g, us* A, int row8, int lp) {
  const ull* p = (const ull*)(g + (size_t)row8 * HH) + lp;
  ull r[8];
  #pragma unroll
  for (int j = 0; j < 8; ++j)
    r[j] = __hip_atomic_load(p + j * 32, __ATOMIC_RELAXED, __HIP_MEMORY_SCOPE_AGENT);
  us* d = A + row8 * ASTR + lp * 4;
  #pragma unroll
  for (int j = 0; j < 8; ++j) *(ull*)(d + j * 128) = r[j];
}

// in-register 4x4 transpose within a lane quad -> 4 cols of row (r16&3)
__device__ __forceinline__ ull quad_pack(float v0, float v1, float v2, float v3, int q) {
  unsigned p01 = (unsigned)f2b(v0) | ((unsigned)f2b(v1) << 16);
  unsigned p23 = (unsigned)f2b(v2) | ((unsigned)f2b(v3) << 16);
  unsigned o01 = __shfl_xor(p01, 2);
  unsigned o23 = __shfl_xor(p23, 2);
  unsigned x = (q < 2) ? p01 : o23;
  unsigned y = (q < 2) ? o01 : p23;
  unsigned ux = __shfl_xor(x, 1);
  unsigned uy = __shfl_xor(y, 1);
  unsigned w0, w1;
  if (q & 1) { w0 = (ux >> 16) | (x & 0xFFFF0000u); w1 = (uy >> 16) | (y & 0xFFFF0000u); }
  else       { w0 = (x & 0xFFFFu) | (ux << 16);     w1 = (y & 0xFFFFu) | (uy << 16); }
  return (ull)w0 | ((ull)w1 << 32);
}

extern "C" __global__ void __launch_bounds__(256, 1)
gru_persistent(const float* __restrict__ X, const float* __restrict__ GK,
               const float* __restrict__ GB, const float* __restrict__ CK,
               const float* __restrict__ CB, float* __restrict__ Y,
               unsigned char* __restrict__ ws) {
  extern __shared__ us lds[];
  us*    Wg  = lds;                          // [64][WPGE] gate h-part (r|u cols)
  us*    Ash = lds + O_ASH;                  // [8][ASTR]
  us*    Xs  = lds + O_XS;                   // [8][XSTR]
  float* ush = (float*)(lds + O_USH);        // u [8][36]
  float* ps  = (float*)(lds + O_PS);         // cand partials [2][8][20]

  const int tid = threadIdx.x, bid = blockIdx.x;
  const int isl = bid & 7, iw = bid >> 3;    // island, WG-in-island (0..31)
  const int lane = tid & 63, w = tid >> 6;
  const int r16 = lane & 15, g4 = lane >> 4;
  const int row8 = tid >> 5, lp = tid & 31;  // staging map
  const int cb = iw * 32;                    // this WG's 32 columns
  const int half = w & 1;                    // gate col-tile within wave pair
  const int tlB = w >> 1, khB = w & 1;       // cand: tile, K-half

  unsigned* hfl = (unsigned*)(ws + (size_t)isl * 4096);
  unsigned* rfl = hfl + 512;                 // +2048 B
  us* hbI  = (us*)(ws + W_HB)  + (size_t)(isl * 8) * HH;
  us* rhbI = (us*)(ws + W_RHB) + (size_t)(isl * 8) * HH;

  // ---- weights -------------------------------------------------------------
  {   // gate h-part: LDS rows 0..31 = r cols cb.., rows 32..63 = u cols
    const int c = tid & 63;
    const size_t gcol = (c < 32) ? (size_t)(cb + c) : (size_t)(1024 + cb + (c - 32));
    for (int k = tid >> 6; k < 1024; k += 4)
      Wg[c * WPGE + k] = f2b(GK[(size_t)(512 + k) * 2048 + gcol]);
  }
  s16x8 wx[16], wc[16];
  {   // gate x-part (own col): waves 0,1 -> r cols; waves 2,3 -> u cols
    const size_t gx = (size_t)(cb + half * 16 + r16) + (w >= 2 ? 1024 : 0);
    #pragma unroll
    for (int c2 = 0; c2 < 16; ++c2) {
      us t0[8];
      #pragma unroll
      for (int e = 0; e < 8; ++e)
        t0[e] = f2b(GK[(size_t)(c2 * 32 + g4 * 8 + e) * 2048 + gx]);
      wx[c2] = (s16x8){(short)t0[0],(short)t0[1],(short)t0[2],(short)t0[3],
                       (short)t0[4],(short)t0[5],(short)t0[6],(short)t0[7]};
    }
  }
  {   // cand h-part (own col, K half khB)
    const size_t ccol = (size_t)(cb + tlB * 16 + r16);
    #pragma unroll
    for (int c2 = 0; c2 < 16; ++c2) {
      us t0[8];
      #pragma unroll
      for (int e = 0; e < 8; ++e)
        t0[e] = f2b(CK[(size_t)(512 + khB * 512 + c2 * 32 + g4 * 8 + e) * 1024 + ccol]);
      wc[c2] = (s16x8){(short)t0[0],(short)t0[1],(short)t0[2],(short)t0[3],
                       (short)t0[4],(short)t0[5],(short)t0[6],(short)t0[7]};
    }
  }
  const float biasG = (w < 2) ? GB[cb + half * 16 + r16]
                              : GB[1024 + cb + half * 16 + r16];
  const float biasC = CB[cb + tlB * 16 + r16];

  // ---- recurrence ----------------------------------------------------------
  float hreg[4] = {0.f, 0.f, 0.f, 0.f};
  bool bad = false;
  float4 px0, px1, px2, px3;
  {
    const float* s = X + (size_t)(isl * 8 + row8) * TT * DD + lp * 16;
    px0 = *(const float4*)s;       px1 = *(const float4*)(s + 4);
    px2 = *(const float4*)(s + 8); px3 = *(const float4*)(s + 12);
  }

  for (int t = 0; t < TT; ++t) {
    {   // Xs(t) from prefetch regs
      us* xd = Xs + row8 * XSTR + lp * 16;
      us8 v0 = { f2b(px0.x), f2b(px0.y), f2b(px0.z), f2b(px0.w),
                 f2b(px1.x), f2b(px1.y), f2b(px1.z), f2b(px1.w) };
      us8 v1 = { f2b(px2.x), f2b(px2.y), f2b(px2.z), f2b(px2.w),
                 f2b(px3.x), f2b(px3.y), f2b(px3.z), f2b(px3.w) };
      *(us8*)xd = v0; *(us8*)(xd + 8) = v1;
    }
    __syncthreads();                                              // S1

    // gate x-part (overlaps the h wait)
    f32x4 a0 = {0.f,0.f,0.f,0.f}, a1 = {0.f,0.f,0.f,0.f};
    {
      const us* arX = Xs + (r16 & 7) * XSTR;
      #pragma unroll
      for (int c2 = 0; c2 < 16; c2 += 2) {
        a0 = __builtin_amdgcn_mfma_f32_16x16x32_bf16(
               *(const s16x8*)(arX + c2 * 32 + g4 * 8), wx[c2], a0, 0, 0, 0);
        a1 = __builtin_amdgcn_mfma_f32_16x16x32_bf16(
               *(const s16x8*)(arX + (c2 + 1) * 32 + g4 * 8), wx[c2 + 1], a1, 0, 0, 0);
      }
    }
    waitf(hfl, (unsigned)t, lane, bad);                 // h(t-1) ready
    stage(hbI, Ash, row8, lp);
    __syncthreads();                                              // S2

    {   // gate h-GEMM K=1024 (wave w -> Wg rows w*16..)
      const us* arB = Ash + (r16 & 7) * ASTR;
      const us* brB = Wg + (w * 16 + r16) * WPGE + g4 * 8;
      #pragma unroll
      for (int c2 = 0; c2 < 32; c2 += 2) {
        a0 = __builtin_amdgcn_mfma_f32_16x16x32_bf16(
               *(const s16x8*)(arB + c2 * 32 + g4 * 8),
               *(const s16x8*)(brB + c2 * 32), a0, 0, 0, 0);
        a1 = __builtin_amdgcn_mfma_f32_16x16x32_bf16(
               *(const s16x8*)(arB + (c2 + 1) * 32 + g4 * 8),
               *(const s16x8*)(brB + (c2 + 1) * 32), a1, 0, 0, 0);
      }
    }
    if (g4 < 2) {
      if (w < 2) {                         // r -> publish r*h (8B quad stores)
        const int colR = cb + half * 16 + r16;
        float rh[4];
        #pragma unroll
        for (int i = 0; i < 4; ++i) {      // C/D: row=g4*4+i, col=r16
          float gg = 1.f / (1.f + __expf(-(a0[i] + a1[i] + biasG)));
          rh[i] = gg * b2f(Ash[(g4 * 4 + i) * ASTR + colR]);
        }
        ull tv = quad_pack(rh[0], rh[1], rh[2], rh[3], r16 & 3);
        __hip_atomic_store(
            (ull*)(rhbI + (size_t)(g4 * 4 + (r16 & 3)) * HH + cb + half * 16 + (r16 & ~3)),
            tv, __ATOMIC_RELAXED, __HIP_MEMORY_SCOPE_AGENT);
      } else {                             // u -> LDS (stays in-WG)
        const int uc = half * 16 + r16;
        #pragma unroll
        for (int i = 0; i < 4; ++i)
          ush[(g4 * 4 + i) * 36 + uc] = 1.f / (1.f + __expf(-(a0[i] + a1[i] + biasG)));
      }
    }
    __syncthreads();                       // S3: vmcnt drain -> rh visible
    if (tid == 0)
      __hip_atomic_store(rfl + iw * 16, (unsigned)(t + 1),
                         __ATOMIC_RELAXED, __HIP_MEMORY_SCOPE_AGENT);

    // ---- phase B: cand over r*h ----
    float xc[4];                           // f32 xp_c from Y slot t (pre-wait)
    if (khB == 0 && g4 < 2) {
      const int colC = cb + tlB * 16 + r16;
      #pragma unroll
      for (int i = 0; i < 4; ++i)
        xc[i] = Y[((size_t)(isl * 8 + g4 * 4 + i) * TT + t) * HH + colC];
    }
    waitf(rfl, (unsigned)(t + 1), lane, bad);
    stage(rhbI, Ash, row8, lp);
    __syncthreads();                                              // S4

    f32x4 c0 = {0.f,0.f,0.f,0.f}, c1 = {0.f,0.f,0.f,0.f};
    {
      const us* arC = Ash + (r16 & 7) * ASTR + khB * 512;
      #pragma unroll
      for (int c2 = 0; c2 < 16; c2 += 2) {
        c0 = __builtin_amdgcn_mfma_f32_16x16x32_bf16(
               *(const s16x8*)(arC + c2 * 32 + g4 * 8), wc[c2], c0, 0, 0, 0);
        c1 = __builtin_amdgcn_mfma_f32_16x16x32_bf16(
               *(const s16x8*)(arC + (c2 + 1) * 32 + g4 * 8), wc[c2 + 1], c1, 0, 0, 0);
      }
    }
    if (khB == 1 && g4 < 2) {              // partials K-half 1 -> LDS
      #pragma unroll
      for (int i = 0; i < 4; ++i)
        ps[tlB * 160 + (g4 * 4 + i) * 20 + r16] = c0[i] + c1[i];
    }
    __syncthreads();                                              // S5
    if (khB == 0 && g4 < 2) {              // blend + publish h
      const int colC = cb + tlB * 16 + r16;
      float hn[4];
      #pragma unroll
      for (int i = 0; i < 4; ++i) {
        int rr = g4 * 4 + i;
        float cv = tanhf(c0[i] + c1[i] + ps[tlB * 160 + rr * 20 + r16] + xc[i] + biasC);
        float uu = ush[rr * 36 + tlB * 16 + r16];
        hn[i] = uu * hreg[i] + (1.f - uu) * cv;
        hreg[i] = hn[i];
        Y[((size_t)(isl * 8 + rr) * TT + t) * HH + colC] = hn[i];
      }
      ull tv = quad_pack(hn[0], hn[1], hn[2], hn[3], r16 & 3);
      __hip_atomic_store(
          (ull*)(hbI + (size_t)(g4 * 4 + (r16 & 3)) * HH + cb + tlB * 16 + (r16 & ~3)),
          tv, __ATOMIC_RELAXED, __HIP_MEMORY_SCOPE_AGENT);
    }
    if (t + 1 < TT) {                      // prefetch x(t+1)
      const float* s = X + ((size_t)(isl * 8 + row8) * TT + (t + 1)) * DD + lp * 16;
      px0 = *(const float4*)s;       px1 = *(const float4*)(s + 4);
      px2 = *(const float4*)(s + 8); px3 = *(const float4*)(s + 12);
    }
    __syncthreads();                       // S6: vmcnt drain -> h visible
    if (tid == 0)
      __hip_atomic_store(hfl + iw * 16, (unsigned)(t + 1),
                         __ATOMIC_RELAXED, __HIP_MEMORY_SCOPE_AGENT);
  }
  if (bad && tid == 0) Y[1] = 31337.f;     // visible failure sentinel
}

// ---- one-time x-projection: Y <- f32(X[32768,512] @ CKc[512,1024]) ---------
extern "C" __global__ void __launch_bounds__(256, 1)
xproj_c(const float* __restrict__ X, const float* __restrict__ CK,
        float* __restrict__ Y) {
  extern __shared__ us lds[];
  us* Bc  = lds;                 // [64][520]
  us* Axs = lds + 64 * 520;      // [16][520]
  const int tid = threadIdx.x, lane = tid & 63, w = tid >> 6;
  const int r16 = lane & 15, g4 = lane >> 4;
  const int nt = blockIdx.x & 15, mb = blockIdx.x >> 4;
  const int n0 = nt * 64;
  const int srow = tid >> 4, slp = tid & 15;

  {
    const int c4 = (tid & 15) * 4;
    for (int k = tid >> 4; k < 512; k += 16) {
      float4 v = *(const float4*)(CK + (size_t)k * HH + n0 + c4);
      Bc[(c4 + 0) * 520 + k] = f2b(v.x);  Bc[(c4 + 1) * 520 + k] = f2b(v.y);
      Bc[(c4 + 2) * 520 + k] = f2b(v.z);  Bc[(c4 + 3) * 520 + k] = f2b(v.w);
    }
  }
  __syncthreads();

  for (int mt = 0; mt < 32; ++mt) {
    const size_t m0 = (size_t)mb * 512 + mt * 16;
    {                                      // stage A [16][512] f32->bf16
      const float* src = X + (m0 + srow) * 512 + slp * 4;
      us* d = Axs + srow * 520 + slp * 4;
      #pragma unroll
      for (int j = 0; j < 8; ++j) {
        float4 v = *(const float4*)(src + j * 64);
        us4 p = { f2b(v.x), f2b(v.y), f2b(v.z), f2b(v.w) };
        *(us4*)(d + j * 64) = p;
      }
    }
    __syncthreads();
    const int ci = w;
    f32x4 ac0 = {0.f,0.f,0.f,0.f}, ac1 = {0.f,0.f,0.f,0.f};
    const us* ar = Axs + r16 * 520 + g4 * 8;
    const us* bc = Bc + (ci * 16 + r16) * 520 + g4 * 8;
    #pragma unroll
    for (int f = 0; f < 16; f += 2) {
      ac0 = __builtin_amdgcn_mfma_f32_16x16x32_bf16(
              *(const s16x8*)(ar + f * 32), *(const s16x8*)(bc + f * 32), ac0, 0,0,0);
      ac1 = __builtin_amdgcn_mfma_f32_16x16x32_bf16(
              *(const s16x8*)(ar + f * 32 + 32), *(const s16x8*)(bc + f * 32 + 32), ac1, 0,0,0);
    }
    #pragma unroll
    for (int i = 0; i < 4; ++i)
      Y[(m0 + g4 * 4 + i) * HH + n0 + ci * 16 + r16] = ac0[i] + ac1[i];
    __syncthreads();
  }
}

extern "C" __global__ void gru_sentinel(float* out, float v) {
  if (blockIdx.x == 0 && threadIdx.x == 0) out[0] = v;
}

extern "C" void kernel_launch(void* const* d_in, const int* in_sizes, int n_in,
                              void* d_out, int out_size, void* d_ws, size_t ws_size,
                              hipStream_t stream) {
  const float* X  = (const float*)d_in[0];
  const float* GK = (const float*)d_in[1];
  const float* GB = (const float*)d_in[2];
  const float* CK = (const float*)d_in[3];
  const float* CB = (const float*)d_in[4];
  float* Y = (float*)d_out;
  unsigned char* wsb = (unsigned char*)d_ws;

  if (ws_size < (size_t)W_END) {
    gru_sentinel<<<1, 64, 0, stream>>>(Y, 1000.f + (float)(ws_size >> 20));
    return;
  }

  // zero flags + hb (h0 = 0) + rhb; deterministic each call
  hipMemsetAsync(d_ws, 0, W_END, stream);

  (void)hipFuncSetAttribute((const void*)xproj_c,
                            hipFuncAttributeMaxDynamicSharedMemorySize, XP_LDSB);
  xproj_c<<<dim3(16 * 64), dim3(256), XP_LDSB, stream>>>(X, CK, Y);

  (void)hipFuncSetAttribute((const void*)gru_persistent,
                            hipFuncAttributeMaxDynamicSharedMemorySize, LDS_BYTES);
  gru_persistent<<<dim3(256), dim3(256), LDS_BYTES, stream>>>(X, GK, GB, CK, CB, Y, wsb);
}